// Round 1
// baseline (537.824 us; speedup 1.0000x reference)
//
#include <hip/hip_runtime.h>
#include <cfloat>

// Problem constants
constexpr int DIM  = 512;     // embedding dim (C)
constexpr int NEMB = 1024;    // number of embeddings (K)
constexpr int HW   = 1024;    // H*W
constexpr int NROW = 32 * HW; // total rows = B*H*W = 32768

// Tiling
constexpr int TM = 64;    // rows per block
constexpr int TN = 128;   // embedding cols per N-chunk
constexpr int KC = 32;    // K-chunk
constexpr int ZS_STRIDE = 68;   // 64 + 4 pad (bank-conflict-free staged writes, keeps 16B align)
constexpr int ES_STRIDE = 132;  // 128 + 4 pad (16B aligned rows)

constexpr long long QCOUNT = (long long)32 * 512 * 32 * 32; // 16777216
constexpr long long SOFF   = QCOUNT;                        // scalar 0.0 slot
constexpr long long IOFF   = SOFF + 1;                      // indices (as float)

__global__ __launch_bounds__(256) void enorm_kernel(const float* __restrict__ e,
                                                    float* __restrict__ enorm) {
    int gid  = blockIdx.x * 256 + threadIdx.x;
    int wave = gid >> 6;
    int lane = gid & 63;
    if (wave >= NEMB) return;
    const float* row = e + (size_t)wave * DIM;
    float4 a = *reinterpret_cast<const float4*>(row + lane * 8);
    float4 b = *reinterpret_cast<const float4*>(row + lane * 8 + 4);
    float s = a.x*a.x + a.y*a.y + a.z*a.z + a.w*a.w
            + b.x*b.x + b.y*b.y + b.z*b.z + b.w*b.w;
    #pragma unroll
    for (int off = 32; off > 0; off >>= 1) s += __shfl_down(s, off, 64);
    if (lane == 0) enorm[wave] = s;
}

union F4 { float4 v; float f[4]; };

__global__ __launch_bounds__(256) void vq_main_kernel(const float* __restrict__ z,
                                                      const float* __restrict__ e,
                                                      const float* __restrict__ enorm,
                                                      float* __restrict__ out) {
    __shared__ float zs[KC][ZS_STRIDE];
    __shared__ float es[KC][ES_STRIDE];
    __shared__ float enorm_l[NEMB];
    __shared__ float best_l[TM][16];
    __shared__ int   idx_l[TM][16];
    __shared__ int   idx_f[TM];

    const int t   = threadIdx.x;
    const int n0  = blockIdx.x * TM;        // first row of this block
    const int b   = n0 >> 10;               // batch index
    const int hw0 = n0 & (HW - 1);          // hw offset within batch
    // z[b][c][hw] : row n (=b*1024+hw) column c lives at zb + c*HW + (hw-hw0)
    const float* zb = z + ((size_t)b * DIM) * HW + hw0;

    // stage embedding norms once
    #pragma unroll
    for (int i = 0; i < 4; ++i) enorm_l[t + i * 256] = enorm[t + i * 256];

    const int rg = t >> 4;   // 0..15 -> rows rg*4 .. rg*4+3
    const int cg = t & 15;   // 0..15 -> cols cg*8 .. cg*8+7 (within N-chunk)

    float best[4];
    int   bidx[4];
    #pragma unroll
    for (int i = 0; i < 4; ++i) { best[i] = FLT_MAX; bidx[i] = 0; }

    // staging coordinates
    const int z_row4 = (t & 15) * 4;  // row quad
    const int z_cl   = t >> 4;        // channel lane 0..15
    const int e_a    = t & 7;         // c quad: c = e_a*4 .. +3
    const int e_keb  = t >> 3;        // 0..31

    for (int nc = 0; nc < NEMB / TN; ++nc) {
        const int k0 = nc * TN;
        float acc[4][8];
        #pragma unroll
        for (int mi = 0; mi < 4; ++mi)
            #pragma unroll
            for (int nj = 0; nj < 8; ++nj) acc[mi][nj] = 0.f;

        for (int kc = 0; kc < DIM / KC; ++kc) {
            const int c0 = kc * KC;
            __syncthreads();
            // ---- stage z chunk: zs[c][row], coalesced 64-float runs along hw
            #pragma unroll
            for (int p = 0; p < 2; ++p) {
                int c = z_cl + p * 16;
                float4 v = *reinterpret_cast<const float4*>(zb + (size_t)(c0 + c) * HW + z_row4);
                *reinterpret_cast<float4*>(&zs[c][z_row4]) = v;
            }
            // ---- stage e chunk transposed: es[c][ke]
            #pragma unroll
            for (int p = 0; p < 4; ++p) {
                int ke = e_keb + p * 32;
                float4 v = *reinterpret_cast<const float4*>(e + (size_t)(k0 + ke) * DIM + c0 + e_a * 4);
                es[e_a * 4 + 0][ke] = v.x;
                es[e_a * 4 + 1][ke] = v.y;
                es[e_a * 4 + 2][ke] = v.z;
                es[e_a * 4 + 3][ke] = v.w;
            }
            __syncthreads();
            // ---- 4x8 micro-tile accumulate
            #pragma unroll
            for (int kk = 0; kk < KC; ++kk) {
                F4 zf, e0, e1;
                zf.v = *reinterpret_cast<const float4*>(&zs[kk][rg * 4]);
                e0.v = *reinterpret_cast<const float4*>(&es[kk][cg * 8]);
                e1.v = *reinterpret_cast<const float4*>(&es[kk][cg * 8 + 4]);
                #pragma unroll
                for (int mi = 0; mi < 4; ++mi) {
                    #pragma unroll
                    for (int nj = 0; nj < 4; ++nj) {
                        acc[mi][nj]     += zf.f[mi] * e0.f[nj];
                        acc[mi][nj + 4] += zf.f[mi] * e1.f[nj];
                    }
                }
            }
        }
        // ---- distances + running argmin for this N-chunk
        #pragma unroll
        for (int mi = 0; mi < 4; ++mi) {
            #pragma unroll
            for (int nj = 0; nj < 8; ++nj) {
                int col = k0 + cg * 8 + nj;
                float dv = enorm_l[col] - 2.0f * acc[mi][nj];
                if (dv < best[mi]) { best[mi] = dv; bidx[mi] = col; }
            }
        }
    }

    // ---- block-level argmin reduction across the 16 col-groups
    __syncthreads();
    #pragma unroll
    for (int mi = 0; mi < 4; ++mi) {
        best_l[rg * 4 + mi][cg] = best[mi];
        idx_l[rg * 4 + mi][cg]  = bidx[mi];
    }
    __syncthreads();
    if (t < TM) {
        float bv = best_l[t][0];
        int   bi = idx_l[t][0];
        #pragma unroll
        for (int c = 1; c < 16; ++c) {
            float v  = best_l[t][c];
            int   ix = idx_l[t][c];
            if (v < bv || (v == bv && ix < bi)) { bv = v; bi = ix; }
        }
        idx_f[t] = bi;
        out[IOFF + n0 + t] = (float)bi;   // index output, as f32
    }
    if (blockIdx.x == 0 && t == 0) out[SOFF] = 0.0f;
    __syncthreads();

    // ---- gather epilogue: out[b][c][hw0+row] = e[idx[row]][c]
    const int row4 = (t & 15) * 4;
    const int i0 = idx_f[row4 + 0];
    const int i1 = idx_f[row4 + 1];
    const int i2 = idx_f[row4 + 2];
    const int i3 = idx_f[row4 + 3];
    #pragma unroll 4
    for (int p = 0; p < 32; ++p) {
        int c = (t >> 4) + (p << 4);
        float4 v;
        v.x = e[(size_t)i0 * DIM + c];
        v.y = e[(size_t)i1 * DIM + c];
        v.z = e[(size_t)i2 * DIM + c];
        v.w = e[(size_t)i3 * DIM + c];
        *reinterpret_cast<float4*>(&out[((size_t)b * DIM + c) * HW + hw0 + row4]) = v;
    }
}

extern "C" void kernel_launch(void* const* d_in, const int* in_sizes, int n_in,
                              void* d_out, int out_size, void* d_ws, size_t ws_size,
                              hipStream_t stream) {
    const float* z = (const float*)d_in[0];
    const float* e = (const float*)d_in[1];
    float* out   = (float*)d_out;
    float* enorm = (float*)d_ws;   // 1024 floats of scratch

    hipLaunchKernelGGL(enorm_kernel, dim3(NEMB / 4), dim3(256), 0, stream, e, enorm);
    hipLaunchKernelGGL(vq_main_kernel, dim3(NROW / TM), dim3(256), 0, stream,
                       z, e, enorm, out);
}

// Round 2
// 465.434 us; speedup vs baseline: 1.1555x; 1.1555x over previous
//
#include <hip/hip_runtime.h>
#include <cfloat>

// Problem constants
constexpr int DIM  = 512;     // embedding dim (C)
constexpr int NEMB = 1024;    // number of embeddings (K)
constexpr int HW   = 1024;    // H*W
constexpr int NROW = 32 * HW; // total rows = B*H*W = 32768

// Tiling
constexpr int TM = 64;    // rows per block
constexpr int TN = 256;   // embedding cols per N-chunk
constexpr int KC = 32;    // K-chunk (channels per stage)
constexpr int ZST = 68;   // zs stride: 64 + 4 pad
constexpr int EST = 260;  // es stride: 256 + 4 pad

constexpr long long QCOUNT = (long long)32 * 512 * 32 * 32; // 16777216
constexpr long long SOFF   = QCOUNT;                        // scalar 0.0 slot
constexpr long long IOFF   = SOFF + 1;                      // indices slot

__global__ __launch_bounds__(256) void enorm_kernel(const float* __restrict__ e,
                                                    float* __restrict__ enorm) {
    int gid  = blockIdx.x * 256 + threadIdx.x;
    int wave = gid >> 6;
    int lane = gid & 63;
    if (wave >= NEMB) return;
    const float* row = e + (size_t)wave * DIM;
    float4 a = *reinterpret_cast<const float4*>(row + lane * 8);
    float4 b = *reinterpret_cast<const float4*>(row + lane * 8 + 4);
    float s = a.x*a.x + a.y*a.y + a.z*a.z + a.w*a.w
            + b.x*b.x + b.y*b.y + b.z*b.z + b.w*b.w;
    #pragma unroll
    for (int off = 32; off > 0; off >>= 1) s += __shfl_down(s, off, 64);
    if (lane == 0) enorm[wave] = s;
}

union F4 { float4 v; float f[4]; };

__global__ __launch_bounds__(256) void vq_main_kernel(const float* __restrict__ z,
                                                      const float* __restrict__ e,
                                                      const float* __restrict__ enorm,
                                                      float* __restrict__ out) {
    __shared__ float zs[KC][ZST];        // zs[c][row] : rows of z, transposed
    __shared__ float es[KC][EST];        // es[c][ke]  : embeddings, transposed
    __shared__ float enorm_l[NEMB];
    __shared__ int   idx_f[TM];

    const int t   = threadIdx.x;
    const int n0  = blockIdx.x * TM;        // first row of this block
    const int b   = n0 >> 10;               // batch index
    const int hw0 = n0 & (HW - 1);          // hw offset within batch
    const float* zb = z + ((size_t)b * DIM) * HW + hw0;

    #pragma unroll
    for (int i = 0; i < 4; ++i) enorm_l[t + i * 256] = enorm[t + i * 256];

    // micro-tile: 8 rows x 8 cols per thread
    const int rg = t >> 5;   // 0..7  -> rows rg*8 .. rg*8+7 (uniform-ish per wave -> LDS broadcast)
    const int cg = t & 31;   // 0..31 -> cols cg*4..+3 and 128+cg*4..+3 (contiguous per phase)

    float best[8];
    int   bidx[8];
    #pragma unroll
    for (int i = 0; i < 8; ++i) { best[i] = FLT_MAX; bidx[i] = 0; }

    // staging coordinates
    const int z_r4 = (t & 15) * 4;  // row quad
    const int z_c  = t >> 4;        // channel 0..15 (+p*16)
    const int e_ke = t >> 3;        // 0..31 (+p*32)
    const int e_c4 = t & 7;         // c quad: c = e_c4*4 .. +3

    for (int nc = 0; nc < NEMB / TN; ++nc) {
        const int k0 = nc * TN;
        float acc[8][8];
        #pragma unroll
        for (int mi = 0; mi < 8; ++mi)
            #pragma unroll
            for (int nj = 0; nj < 8; ++nj) acc[mi][nj] = 0.f;

        for (int kc = 0; kc < DIM / KC; ++kc) {
            const int c0 = kc * KC;
            __syncthreads();
            // ---- stage z chunk: zs[c][row]; global reads + LDS writes both contiguous
            #pragma unroll
            for (int p = 0; p < 2; ++p) {
                int c = z_c + p * 16;
                float4 v = *reinterpret_cast<const float4*>(zb + (size_t)(c0 + c) * HW + z_r4);
                *reinterpret_cast<float4*>(&zs[c][z_r4]) = v;
            }
            // ---- stage e chunk transposed: es[c][ke]
            #pragma unroll
            for (int p = 0; p < 8; ++p) {
                int ke = e_ke + p * 32;
                float4 v = *reinterpret_cast<const float4*>(e + (size_t)(k0 + ke) * DIM + c0 + e_c4 * 4);
                es[e_c4 * 4 + 0][ke] = v.x;
                es[e_c4 * 4 + 1][ke] = v.y;
                es[e_c4 * 4 + 2][ke] = v.z;
                es[e_c4 * 4 + 3][ke] = v.w;
            }
            __syncthreads();
            // ---- 8x8 micro-tile accumulate
            #pragma unroll
            for (int kk = 0; kk < KC; ++kk) {
                F4 zf0, zf1, ef0, ef1;
                zf0.v = *reinterpret_cast<const float4*>(&zs[kk][rg * 8]);
                zf1.v = *reinterpret_cast<const float4*>(&zs[kk][rg * 8 + 4]);
                ef0.v = *reinterpret_cast<const float4*>(&es[kk][cg * 4]);
                ef1.v = *reinterpret_cast<const float4*>(&es[kk][128 + cg * 4]);
                #pragma unroll
                for (int mi = 0; mi < 4; ++mi) {
                    #pragma unroll
                    for (int nj = 0; nj < 4; ++nj) {
                        acc[mi][nj]         += zf0.f[mi] * ef0.f[nj];
                        acc[mi][nj + 4]     += zf0.f[mi] * ef1.f[nj];
                        acc[mi + 4][nj]     += zf1.f[mi] * ef0.f[nj];
                        acc[mi + 4][nj + 4] += zf1.f[mi] * ef1.f[nj];
                    }
                }
            }
        }
        // ---- distances + running argmin for this N-chunk (cols ascending for tie-break)
        #pragma unroll
        for (int mi = 0; mi < 8; ++mi) {
            #pragma unroll
            for (int nj = 0; nj < 8; ++nj) {
                int col = k0 + (nj < 4 ? cg * 4 + nj : 128 + cg * 4 + (nj - 4));
                float dv = enorm_l[col] - 2.0f * acc[mi][nj];
                if (dv < best[mi]) { best[mi] = dv; bidx[mi] = col; }
            }
        }
    }

    // ---- block-level argmin reduction across the 32 col-groups
    // reuse dead es buffer: best_l[64][33], idx_l[64][33] (stride 33 -> conflict-free)
    __syncthreads();
    float* best_l = reinterpret_cast<float*>(es);
    int*   idx_l  = reinterpret_cast<int*>(reinterpret_cast<char*>(es) + (size_t)TM * 33 * 4);
    #pragma unroll
    for (int mi = 0; mi < 8; ++mi) {
        int row = rg * 8 + mi;
        best_l[row * 33 + cg] = best[mi];
        idx_l[row * 33 + cg]  = bidx[mi];
    }
    __syncthreads();
    if (t < TM) {
        float bv = best_l[t * 33];
        int   bi = idx_l[t * 33];
        #pragma unroll
        for (int c = 1; c < 32; ++c) {
            float v  = best_l[t * 33 + c];
            int   ix = idx_l[t * 33 + c];
            if (v < bv || (v == bv && ix < bi)) { bv = v; bi = ix; }
        }
        idx_f[t] = bi;
        out[IOFF + n0 + t] = (float)bi;   // index output
    }
    if (blockIdx.x == 0 && t == 0) out[SOFF] = 0.0f;
    __syncthreads();

    // ---- gather epilogue: out[b][c][hw0+row] = e[idx[row]][c]
    const int row4 = (t & 15) * 4;
    const int i0 = idx_f[row4 + 0];
    const int i1 = idx_f[row4 + 1];
    const int i2 = idx_f[row4 + 2];
    const int i3 = idx_f[row4 + 3];
    #pragma unroll 4
    for (int p = 0; p < 32; ++p) {
        int c = (t >> 4) + (p << 4);
        float4 v;
        v.x = e[(size_t)i0 * DIM + c];
        v.y = e[(size_t)i1 * DIM + c];
        v.z = e[(size_t)i2 * DIM + c];
        v.w = e[(size_t)i3 * DIM + c];
        *reinterpret_cast<float4*>(&out[((size_t)b * DIM + c) * HW + hw0 + row4]) = v;
    }
}

extern "C" void kernel_launch(void* const* d_in, const int* in_sizes, int n_in,
                              void* d_out, int out_size, void* d_ws, size_t ws_size,
                              hipStream_t stream) {
    const float* z = (const float*)d_in[0];
    const float* e = (const float*)d_in[1];
    float* out   = (float*)d_out;
    float* enorm = (float*)d_ws;   // 1024 floats of scratch

    hipLaunchKernelGGL(enorm_kernel, dim3(NEMB / 4), dim3(256), 0, stream, e, enorm);
    hipLaunchKernelGGL(vq_main_kernel, dim3(NROW / TM), dim3(256), 0, stream,
                       z, e, enorm, out);
}

// Round 3
// 385.323 us; speedup vs baseline: 1.3958x; 1.2079x over previous
//
#include <hip/hip_runtime.h>
#include <cfloat>

typedef short  bf16x8 __attribute__((ext_vector_type(8)));
typedef float  f32x4  __attribute__((ext_vector_type(4)));
typedef unsigned int  uint;
typedef unsigned short ushort;

// Problem constants
constexpr int DIM  = 512;
constexpr int NEMB = 1024;
constexpr int HW   = 1024;
constexpr int NROW = 32 * HW;   // 32768

constexpr long long QCOUNT = (long long)32 * 512 * 32 * 32; // 16777216
constexpr long long SOFF   = QCOUNT;
constexpr long long IOFF   = SOFF + 1;

// ---------------- ws layout (bytes) ----------------
// zt_hi: 512 mb-tiles x 8 kc x (64r x 64k bf16 = 8192B)   = 32 MB
// zt_lo: same                                              = 32 MB
// et_hi: 8 nc x 8 kc x (128r x 64k bf16 = 16384B)          = 1 MB
// et_lo: same                                              = 1 MB
constexpr size_t WS_ZHI   = 0;
constexpr size_t WS_ZLO   = 33554432;
constexpr size_t WS_EHI   = 67108864;
constexpr size_t WS_ELO   = 68157440;
constexpr size_t WS_ENORM = 69206016;
constexpr size_t WS_CNT   = 69210112;
constexpr size_t WS_LIST  = 69210368;
constexpr size_t WS_NEED  = WS_LIST + (size_t)NROW * 4;

constexpr float DELTA = 0.125f;  // recheck margin (>>200x bf16-split error bound)

// ---------------- helpers ----------------
__device__ __forceinline__ ushort bf16_rne(float x) {
    union { float f; uint u; } a; a.f = x;
    uint t = a.u + 0x7FFFu + ((a.u >> 16) & 1u);
    return (ushort)(t >> 16);
}
__device__ __forceinline__ float bf16_to_f(ushort h) {
    union { float f; uint u; } a; a.u = ((uint)h) << 16;
    return a.f;
}
__device__ __forceinline__ void gld16(const void* g, void* l) {
    __builtin_amdgcn_global_load_lds(
        (const __attribute__((address_space(1))) void*)g,
        (__attribute__((address_space(3))) void*)l, 16, 0, 0);
}
union PK8 { bf16x8 v; ushort u[8]; };

// ---------------- P1: embedding norms + counter zero ----------------
__global__ __launch_bounds__(256) void enorm_prep(const float* __restrict__ e,
                                                  float* __restrict__ enorm,
                                                  int* __restrict__ cnt) {
    if (blockIdx.x == 0 && threadIdx.x == 0) *cnt = 0;
    int gid  = blockIdx.x * 256 + threadIdx.x;
    int wave = gid >> 6;
    int lane = gid & 63;
    if (wave >= NEMB) return;
    const float* row = e + (size_t)wave * DIM;
    float4 a = *reinterpret_cast<const float4*>(row + lane * 8);
    float4 b = *reinterpret_cast<const float4*>(row + lane * 8 + 4);
    float s = a.x*a.x + a.y*a.y + a.z*a.z + a.w*a.w
            + b.x*b.x + b.y*b.y + b.z*b.z + b.w*b.w;
    #pragma unroll
    for (int off = 32; off > 0; off >>= 1) s += __shfl_down(s, off, 64);
    if (lane == 0) enorm[wave] = s;
}

// ---------------- P2: e -> et_hi / et_lo swizzled tiles ----------------
__global__ __launch_bounds__(256) void eprep(const float* __restrict__ e,
                                             char* __restrict__ et_hi,
                                             char* __restrict__ et_lo) {
    int t  = blockIdx.x * 256 + threadIdx.x;  // 0..65535
    int ke = t >> 6;
    int kb = t & 63;                           // global k-granule 0..63
    const float* src = e + (size_t)ke * DIM + kb * 8;
    PK8 h, lo;
    #pragma unroll
    for (int j = 0; j < 8; ++j) {
        float v = src[j];
        ushort hh = bf16_rne(v);
        h.u[j]  = hh;
        lo.u[j] = bf16_rne(v - bf16_to_f(hh));
    }
    int nc = ke >> 7, r = ke & 127, kc = kb >> 3, kbl = kb & 7;
    size_t byte = ((size_t)(nc * 8 + kc)) * 16384 + (size_t)r * 128
                + (size_t)((kbl ^ (r & 7)) << 4);
    *reinterpret_cast<bf16x8*>(et_hi + byte) = h.v;
    *reinterpret_cast<bf16x8*>(et_lo + byte) = lo.v;
}

// ---------------- P3: z -> zt_hi / zt_lo swizzled tiles (with transpose) ----
__global__ __launch_bounds__(256) void zprep(const float* __restrict__ z,
                                             char* __restrict__ zt_hi,
                                             char* __restrict__ zt_lo) {
    __shared__ float ls[64][65];
    const int bx = blockIdx.x;
    const int mb = bx >> 3, kc = bx & 7;
    const int n0 = mb * 64;
    const int b  = n0 >> 10;
    const int hw0 = n0 & (HW - 1);
    const int t = threadIdx.x;
    const int c4 = t >> 6, lane = t & 63;
    #pragma unroll
    for (int rnd = 0; rnd < 16; ++rnd) {
        int cl = c4 + rnd * 4;
        ls[cl][lane] = z[((size_t)(b * DIM + kc * 64 + cl)) * HW + hw0 + lane];
    }
    __syncthreads();
    size_t tb = ((size_t)mb * 8 + kc) * 8192;
    for (int g = t; g < 512; g += 256) {
        int r = g >> 3, kbl = g & 7;
        PK8 h, lo;
        #pragma unroll
        for (int j = 0; j < 8; ++j) {
            float v = ls[kbl * 8 + j][r];
            ushort hh = bf16_rne(v);
            h.u[j]  = hh;
            lo.u[j] = bf16_rne(v - bf16_to_f(hh));
        }
        size_t byte = tb + (size_t)r * 128 + (size_t)((kbl ^ (r & 7)) << 4);
        *reinterpret_cast<bf16x8*>(zt_hi + byte) = h.v;
        *reinterpret_cast<bf16x8*>(zt_lo + byte) = lo.v;
    }
}

// ---------------- Main: bf16-split MFMA distance + argmin + gather ----------
__global__ __launch_bounds__(256, 2) void vq_mfma(const char* __restrict__ zt_hi,
                                                  const char* __restrict__ zt_lo,
                                                  const char* __restrict__ et_hi,
                                                  const char* __restrict__ et_lo,
                                                  const float* __restrict__ enorm,
                                                  const float* __restrict__ e,
                                                  float* __restrict__ out,
                                                  int* __restrict__ cnt,
                                                  int* __restrict__ list) {
    __shared__ __align__(16) char sAh[8192];
    __shared__ __align__(16) char sAl[8192];
    __shared__ __align__(16) char sBh[16384];
    __shared__ __align__(16) char sBl[16384];
    __shared__ float red_b1[64][2];
    __shared__ float red_b2[64][2];
    __shared__ int   red_i1[64][2];
    __shared__ int   idx_f[64];

    const int t = threadIdx.x;
    const int w = t >> 6, l = t & 63;
    const int lr = l & 15, hg = l >> 4;
    const int wr = (w >> 1) * 32;   // wave row offset (0 or 32)
    const int wc = (w & 1) * 64;    // wave col offset (0 or 64)
    const int mb = blockIdx.x;
    const int n0 = mb * 64;

    float b1[8], b2[8]; int i1[8];
    #pragma unroll
    for (int s = 0; s < 8; ++s) { b1[s] = FLT_MAX; b2[s] = FLT_MAX; i1[s] = 0; }

    const size_t tAbase = (size_t)mb * 8 * 8192;

    for (int nc = 0; nc < 8; ++nc) {
        f32x4 acc[2][4];
        #pragma unroll
        for (int m = 0; m < 2; ++m)
            #pragma unroll
            for (int n = 0; n < 4; ++n) acc[m][n] = (f32x4)(0.f);

        for (int kc = 0; kc < 8; ++kc) {
            __syncthreads();
            {   // stage A (hi+lo: 2x8KB) and B (hi+lo: 2x16KB) linearly
                const char* srcAh = zt_hi + tAbase + (size_t)kc * 8192;
                const char* srcAl = zt_lo + tAbase + (size_t)kc * 8192;
                size_t tB = ((size_t)(nc * 8 + kc)) * 16384;
                const char* srcBh = et_hi + tB;
                const char* srcBl = et_lo + tB;
                #pragma unroll
                for (int p = 0; p < 2; ++p) {
                    int off = (p * 256 + t) * 16;
                    gld16(srcAh + off, sAh + off);
                    gld16(srcAl + off, sAl + off);
                }
                #pragma unroll
                for (int p = 0; p < 4; ++p) {
                    int off = (p * 256 + t) * 16;
                    gld16(srcBh + off, sBh + off);
                    gld16(srcBl + off, sBl + off);
                }
            }
            __syncthreads();
            #pragma unroll
            for (int ks = 0; ks < 2; ++ks) {
                const int kb = ks * 4 + hg;
                bf16x8 ah[2], al[2], bh[4], bl[4];
                #pragma unroll
                for (int m = 0; m < 2; ++m) {
                    int r = wr + m * 16 + lr;
                    int off = r * 128 + ((kb ^ (r & 7)) << 4);
                    ah[m] = *reinterpret_cast<const bf16x8*>(sAh + off);
                    al[m] = *reinterpret_cast<const bf16x8*>(sAl + off);
                }
                #pragma unroll
                for (int n = 0; n < 4; ++n) {
                    int r = wc + n * 16 + lr;
                    int off = r * 128 + ((kb ^ (r & 7)) << 4);
                    bh[n] = *reinterpret_cast<const bf16x8*>(sBh + off);
                    bl[n] = *reinterpret_cast<const bf16x8*>(sBl + off);
                }
                #pragma unroll
                for (int m = 0; m < 2; ++m)
                    #pragma unroll
                    for (int n = 0; n < 4; ++n)
                        acc[m][n] = __builtin_amdgcn_mfma_f32_16x16x32_bf16(ah[m], bh[n], acc[m][n], 0, 0, 0);
                #pragma unroll
                for (int m = 0; m < 2; ++m)
                    #pragma unroll
                    for (int n = 0; n < 4; ++n)
                        acc[m][n] = __builtin_amdgcn_mfma_f32_16x16x32_bf16(ah[m], bl[n], acc[m][n], 0, 0, 0);
                #pragma unroll
                for (int m = 0; m < 2; ++m)
                    #pragma unroll
                    for (int n = 0; n < 4; ++n)
                        acc[m][n] = __builtin_amdgcn_mfma_f32_16x16x32_bf16(al[m], bh[n], acc[m][n], 0, 0, 0);
            }
        }
        // per-nc epilogue: distances + running best-2 argmin
        #pragma unroll
        for (int n = 0; n < 4; ++n) {
            int col = nc * 128 + wc + n * 16 + lr;
            float en = enorm[col];
            #pragma unroll
            for (int m = 0; m < 2; ++m) {
                #pragma unroll
                for (int q = 0; q < 4; ++q) {
                    float dv = en - 2.0f * acc[m][n][q];
                    int s = m * 4 + q;
                    if (dv < b1[s]) { b2[s] = b1[s]; b1[s] = dv; i1[s] = col; }
                    else if (dv < b2[s]) b2[s] = dv;
                }
            }
        }
    }

    // cross-lane butterfly over the 16 column-lanes that share each row
    #pragma unroll
    for (int s = 0; s < 8; ++s) {
        #pragma unroll
        for (int off = 1; off <= 8; off <<= 1) {
            float ob1 = __shfl_xor(b1[s], off, 64);
            int   oi1 = __shfl_xor(i1[s], off, 64);
            float ob2 = __shfl_xor(b2[s], off, 64);
            if (ob1 < b1[s] || (ob1 == b1[s] && oi1 < i1[s])) {
                b2[s] = fminf(b1[s], ob2);
                b1[s] = ob1; i1[s] = oi1;
            } else {
                b2[s] = fminf(b2[s], ob1);
            }
        }
    }
    if (lr == 0) {
        #pragma unroll
        for (int s = 0; s < 8; ++s) {
            int row = wr + (s >> 2) * 16 + hg * 4 + (s & 3);
            red_b1[row][w & 1] = b1[s];
            red_b2[row][w & 1] = b2[s];
            red_i1[row][w & 1] = i1[s];
        }
    }
    __syncthreads();
    if (t < 64) {
        float a1 = red_b1[t][0], a2 = red_b2[t][0]; int ai = red_i1[t][0];
        float c1 = red_b1[t][1], c2 = red_b2[t][1]; int ci = red_i1[t][1];
        float B1, B2; int I1;
        if (c1 < a1 || (c1 == a1 && ci < ai)) { B1 = c1; I1 = ci; B2 = fminf(a1, c2); }
        else                                   { B1 = a1; I1 = ai; B2 = fminf(a2, c1); }
        idx_f[t] = I1;
        out[IOFF + n0 + t] = (float)I1;
        if (B2 - B1 < DELTA) {
            int pos = atomicAdd(cnt, 1);
            list[pos] = n0 + t;
        }
    }
    if (mb == 0 && t == 0) out[SOFF] = 0.0f;
    __syncthreads();

    // gather epilogue: out[b][c][hw0+row] = e[idx[row]][c]
    const int b   = n0 >> 10;
    const int hw0 = n0 & (HW - 1);
    const int row4 = (t & 15) * 4;
    const int i0 = idx_f[row4 + 0];
    const int i1g = idx_f[row4 + 1];
    const int i2 = idx_f[row4 + 2];
    const int i3 = idx_f[row4 + 3];
    #pragma unroll 4
    for (int p = 0; p < 32; ++p) {
        int c = (t >> 4) + (p << 4);
        float4 v;
        v.x = e[(size_t)i0  * DIM + c];
        v.y = e[(size_t)i1g * DIM + c];
        v.z = e[(size_t)i2  * DIM + c];
        v.w = e[(size_t)i3  * DIM + c];
        *reinterpret_cast<float4*>(&out[((size_t)(b * DIM + c)) * HW + hw0 + row4]) = v;
    }
}

// ---------------- Recheck: exact fp32 re-scan of flagged rows ----------------
__global__ __launch_bounds__(256) void recheck(const float* __restrict__ z,
                                               const float* __restrict__ e,
                                               const float* __restrict__ enorm,
                                               const int* __restrict__ cnt,
                                               const int* __restrict__ list,
                                               float* __restrict__ out) {
    __shared__ float zrow[512];
    __shared__ float wbest[4];
    __shared__ int   wbi[4];
    __shared__ int   s_fbi;
    const int t = threadIdx.x;
    const int w = t >> 6, l = t & 63;
    const int count = *cnt;
    for (int i = blockIdx.x; i < count; i += gridDim.x) {
        const int row = list[i];
        const int b = row >> 10;
        const int hw = row & (HW - 1);
        __syncthreads();
        zrow[t]       = z[((size_t)(b * DIM + t))       * HW + hw];
        zrow[t + 256] = z[((size_t)(b * DIM + t + 256)) * HW + hw];
        __syncthreads();
        float best = FLT_MAX; int bi = 0;
        const float4* zr = reinterpret_cast<const float4*>(zrow);
        for (int jj = 0; jj < 256; ++jj) {
            int ke = w * 256 + jj;
            const float4* ep = reinterpret_cast<const float4*>(e + (size_t)ke * DIM);
            float4 e0 = ep[l * 2], e1 = ep[l * 2 + 1];
            float4 z0 = zr[l * 2], z1 = zr[l * 2 + 1];
            float s = e0.x*z0.x + e0.y*z0.y + e0.z*z0.z + e0.w*z0.w
                    + e1.x*z1.x + e1.y*z1.y + e1.z*z1.z + e1.w*z1.w;
            #pragma unroll
            for (int off = 32; off > 0; off >>= 1) s += __shfl_xor(s, off, 64);
            float dist = enorm[ke] - 2.0f * s;
            if (dist < best) { best = dist; bi = ke; }
        }
        if (l == 0) { wbest[w] = best; wbi[w] = bi; }
        __syncthreads();
        if (t == 0) {
            float fb = wbest[0]; int fi = wbi[0];
            #pragma unroll
            for (int ww = 1; ww < 4; ++ww) {
                if (wbest[ww] < fb) { fb = wbest[ww]; fi = wbi[ww]; }
            }
            s_fbi = fi;
            out[IOFF + row] = (float)fi;
        }
        __syncthreads();
        const int fbi = s_fbi;
        out[((size_t)(b * DIM + t))       * HW + hw] = e[(size_t)fbi * DIM + t];
        out[((size_t)(b * DIM + t + 256)) * HW + hw] = e[(size_t)fbi * DIM + t + 256];
    }
}

// ======================= fp32 fallback path (round-2, proven) ================
constexpr int TM = 64;
constexpr int TN = 256;
constexpr int KC = 32;
constexpr int ZST = 68;
constexpr int EST = 260;

union F4 { float4 v; float f[4]; };

__global__ __launch_bounds__(256) void enorm_kernel(const float* __restrict__ e,
                                                    float* __restrict__ enorm) {
    int gid  = blockIdx.x * 256 + threadIdx.x;
    int wave = gid >> 6;
    int lane = gid & 63;
    if (wave >= NEMB) return;
    const float* row = e + (size_t)wave * DIM;
    float4 a = *reinterpret_cast<const float4*>(row + lane * 8);
    float4 b = *reinterpret_cast<const float4*>(row + lane * 8 + 4);
    float s = a.x*a.x + a.y*a.y + a.z*a.z + a.w*a.w
            + b.x*b.x + b.y*b.y + b.z*b.z + b.w*b.w;
    #pragma unroll
    for (int off = 32; off > 0; off >>= 1) s += __shfl_down(s, off, 64);
    if (lane == 0) enorm[wave] = s;
}

__global__ __launch_bounds__(256) void vq_main_kernel(const float* __restrict__ z,
                                                      const float* __restrict__ e,
                                                      const float* __restrict__ enorm,
                                                      float* __restrict__ out) {
    __shared__ float zs[KC][ZST];
    __shared__ float es[KC][EST];
    __shared__ float enorm_l[NEMB];
    __shared__ int   idx_f[TM];

    const int t   = threadIdx.x;
    const int n0  = blockIdx.x * TM;
    const int b   = n0 >> 10;
    const int hw0 = n0 & (HW - 1);
    const float* zb = z + ((size_t)b * DIM) * HW + hw0;

    #pragma unroll
    for (int i = 0; i < 4; ++i) enorm_l[t + i * 256] = enorm[t + i * 256];

    const int rg = t >> 5;
    const int cg = t & 31;

    float best[8];
    int   bidx[8];
    #pragma unroll
    for (int i = 0; i < 8; ++i) { best[i] = FLT_MAX; bidx[i] = 0; }

    const int z_r4 = (t & 15) * 4;
    const int z_c  = t >> 4;
    const int e_ke = t >> 3;
    const int e_c4 = t & 7;

    for (int nc = 0; nc < NEMB / TN; ++nc) {
        const int k0 = nc * TN;
        float acc[8][8];
        #pragma unroll
        for (int mi = 0; mi < 8; ++mi)
            #pragma unroll
            for (int nj = 0; nj < 8; ++nj) acc[mi][nj] = 0.f;

        for (int kc = 0; kc < DIM / KC; ++kc) {
            const int c0 = kc * KC;
            __syncthreads();
            #pragma unroll
            for (int p = 0; p < 2; ++p) {
                int c = z_c + p * 16;
                float4 v = *reinterpret_cast<const float4*>(zb + (size_t)(c0 + c) * HW + z_r4);
                *reinterpret_cast<float4*>(&zs[c][z_r4]) = v;
            }
            #pragma unroll
            for (int p = 0; p < 8; ++p) {
                int ke = e_ke + p * 32;
                float4 v = *reinterpret_cast<const float4*>(e + (size_t)(k0 + ke) * DIM + c0 + e_c4 * 4);
                es[e_c4 * 4 + 0][ke] = v.x;
                es[e_c4 * 4 + 1][ke] = v.y;
                es[e_c4 * 4 + 2][ke] = v.z;
                es[e_c4 * 4 + 3][ke] = v.w;
            }
            __syncthreads();
            #pragma unroll
            for (int kk = 0; kk < KC; ++kk) {
                F4 zf0, zf1, ef0, ef1;
                zf0.v = *reinterpret_cast<const float4*>(&zs[kk][rg * 8]);
                zf1.v = *reinterpret_cast<const float4*>(&zs[kk][rg * 8 + 4]);
                ef0.v = *reinterpret_cast<const float4*>(&es[kk][cg * 4]);
                ef1.v = *reinterpret_cast<const float4*>(&es[kk][128 + cg * 4]);
                #pragma unroll
                for (int mi = 0; mi < 4; ++mi) {
                    #pragma unroll
                    for (int nj = 0; nj < 4; ++nj) {
                        acc[mi][nj]         += zf0.f[mi] * ef0.f[nj];
                        acc[mi][nj + 4]     += zf0.f[mi] * ef1.f[nj];
                        acc[mi + 4][nj]     += zf1.f[mi] * ef0.f[nj];
                        acc[mi + 4][nj + 4] += zf1.f[mi] * ef1.f[nj];
                    }
                }
            }
        }
        #pragma unroll
        for (int mi = 0; mi < 8; ++mi) {
            #pragma unroll
            for (int nj = 0; nj < 8; ++nj) {
                int col = k0 + (nj < 4 ? cg * 4 + nj : 128 + cg * 4 + (nj - 4));
                float dv = enorm_l[col] - 2.0f * acc[mi][nj];
                if (dv < best[mi]) { best[mi] = dv; bidx[mi] = col; }
            }
        }
    }

    __syncthreads();
    float* best_l = reinterpret_cast<float*>(es);
    int*   idx_l  = reinterpret_cast<int*>(reinterpret_cast<char*>(es) + (size_t)TM * 33 * 4);
    #pragma unroll
    for (int mi = 0; mi < 8; ++mi) {
        int row = rg * 8 + mi;
        best_l[row * 33 + cg] = best[mi];
        idx_l[row * 33 + cg]  = bidx[mi];
    }
    __syncthreads();
    if (t < TM) {
        float bv = best_l[t * 33];
        int   bi = idx_l[t * 33];
        #pragma unroll
        for (int c = 1; c < 32; ++c) {
            float v  = best_l[t * 33 + c];
            int   ix = idx_l[t * 33 + c];
            if (v < bv || (v == bv && ix < bi)) { bv = v; bi = ix; }
        }
        idx_f[t] = bi;
        out[IOFF + n0 + t] = (float)bi;
    }
    if (blockIdx.x == 0 && t == 0) out[SOFF] = 0.0f;
    __syncthreads();

    const int row4 = (t & 15) * 4;
    const int i0 = idx_f[row4 + 0];
    const int i1 = idx_f[row4 + 1];
    const int i2 = idx_f[row4 + 2];
    const int i3 = idx_f[row4 + 3];
    #pragma unroll 4
    for (int p = 0; p < 32; ++p) {
        int c = (t >> 4) + (p << 4);
        float4 v;
        v.x = e[(size_t)i0 * DIM + c];
        v.y = e[(size_t)i1 * DIM + c];
        v.z = e[(size_t)i2 * DIM + c];
        v.w = e[(size_t)i3 * DIM + c];
        *reinterpret_cast<float4*>(&out[((size_t)(b * DIM + c)) * HW + hw0 + row4]) = v;
    }
}

// ---------------- host launcher ----------------
extern "C" void kernel_launch(void* const* d_in, const int* in_sizes, int n_in,
                              void* d_out, int out_size, void* d_ws, size_t ws_size,
                              hipStream_t stream) {
    const float* z = (const float*)d_in[0];
    const float* e = (const float*)d_in[1];
    float* out = (float*)d_out;
    char*  ws  = (char*)d_ws;

    if (ws_size >= WS_NEED) {
        char*  zt_hi = ws + WS_ZHI;
        char*  zt_lo = ws + WS_ZLO;
        char*  et_hi = ws + WS_EHI;
        char*  et_lo = ws + WS_ELO;
        float* enorm = (float*)(ws + WS_ENORM);
        int*   cnt   = (int*)(ws + WS_CNT);
        int*   list  = (int*)(ws + WS_LIST);

        hipLaunchKernelGGL(enorm_prep, dim3(NEMB / 4), dim3(256), 0, stream, e, enorm, cnt);
        hipLaunchKernelGGL(eprep,      dim3(256),      dim3(256), 0, stream, e, et_hi, et_lo);
        hipLaunchKernelGGL(zprep,      dim3(4096),     dim3(256), 0, stream, z, zt_hi, zt_lo);
        hipLaunchKernelGGL(vq_mfma,    dim3(NROW / 64), dim3(256), 0, stream,
                           zt_hi, zt_lo, et_hi, et_lo, enorm, e, out, cnt, list);
        hipLaunchKernelGGL(recheck,    dim3(128),      dim3(256), 0, stream,
                           z, e, enorm, cnt, list, out);
    } else {
        float* enorm = (float*)ws;
        hipLaunchKernelGGL(enorm_kernel,   dim3(NEMB / 4), dim3(256), 0, stream, e, enorm);
        hipLaunchKernelGGL(vq_main_kernel, dim3(NROW / TM), dim3(256), 0, stream,
                           z, e, enorm, out);
    }
}

// Round 4
// 328.389 us; speedup vs baseline: 1.6378x; 1.1734x over previous
//
#include <hip/hip_runtime.h>
#include <cfloat>

typedef short  bf16x8 __attribute__((ext_vector_type(8)));
typedef float  f32x4  __attribute__((ext_vector_type(4)));
typedef unsigned int  uint;
typedef unsigned short ushort;

// Problem constants
constexpr int DIM  = 512;
constexpr int NEMB = 1024;
constexpr int HW   = 1024;
constexpr int NROW = 32 * HW;   // 32768

constexpr long long QCOUNT = (long long)32 * 512 * 32 * 32; // 16777216
constexpr long long SOFF   = QCOUNT;
constexpr long long IOFF   = SOFF + 1;

// ---------------- ws layout (bytes) ----------------
constexpr size_t WS_ZHI   = 0;
constexpr size_t WS_ZLO   = 33554432;
constexpr size_t WS_EHI   = 67108864;
constexpr size_t WS_ELO   = 68157440;
constexpr size_t WS_ENORM = 69206016;
constexpr size_t WS_CNT   = 69210112;
constexpr size_t WS_LIST  = 69210368;
constexpr size_t WS_NEED  = WS_LIST + (size_t)NROW * 4;

constexpr float DELTA = 0.125f;  // recheck margin (>>100x bf16-split error bound)

// ---------------- helpers ----------------
__device__ __forceinline__ ushort bf16_rne(float x) {
    union { float f; uint u; } a; a.f = x;
    uint t = a.u + 0x7FFFu + ((a.u >> 16) & 1u);
    return (ushort)(t >> 16);
}
__device__ __forceinline__ float bf16_to_f(ushort h) {
    union { float f; uint u; } a; a.u = ((uint)h) << 16;
    return a.f;
}
__device__ __forceinline__ void gld16(const void* g, void* l) {
    __builtin_amdgcn_global_load_lds(
        (const __attribute__((address_space(1))) void*)g,
        (__attribute__((address_space(3))) void*)l, 16, 0, 0);
}
union PK8 { bf16x8 v; ushort u[8]; };

// ---------------- P1: embedding norms + counter zero ----------------
__global__ __launch_bounds__(256) void enorm_prep(const float* __restrict__ e,
                                                  float* __restrict__ enorm,
                                                  int* __restrict__ cnt) {
    if (blockIdx.x == 0 && threadIdx.x == 0) *cnt = 0;
    int gid  = blockIdx.x * 256 + threadIdx.x;
    int wave = gid >> 6;
    int lane = gid & 63;
    if (wave >= NEMB) return;
    const float* row = e + (size_t)wave * DIM;
    float4 a = *reinterpret_cast<const float4*>(row + lane * 8);
    float4 b = *reinterpret_cast<const float4*>(row + lane * 8 + 4);
    float s = a.x*a.x + a.y*a.y + a.z*a.z + a.w*a.w
            + b.x*b.x + b.y*b.y + b.z*b.z + b.w*b.w;
    #pragma unroll
    for (int off = 32; off > 0; off >>= 1) s += __shfl_down(s, off, 64);
    if (lane == 0) enorm[wave] = s;
}

// ---------------- P2: e -> et_hi / et_lo swizzled tiles ----------------
__global__ __launch_bounds__(256) void eprep(const float* __restrict__ e,
                                             char* __restrict__ et_hi,
                                             char* __restrict__ et_lo) {
    int t  = blockIdx.x * 256 + threadIdx.x;  // 0..65535
    int ke = t >> 6;
    int kb = t & 63;                           // global k-granule 0..63
    const float* src = e + (size_t)ke * DIM + kb * 8;
    PK8 h, lo;
    #pragma unroll
    for (int j = 0; j < 8; ++j) {
        float v = src[j];
        ushort hh = bf16_rne(v);
        h.u[j]  = hh;
        lo.u[j] = bf16_rne(v - bf16_to_f(hh));
    }
    int nc = ke >> 7, r = ke & 127, kc = kb >> 3, kbl = kb & 7;
    size_t byte = ((size_t)(nc * 8 + kc)) * 16384 + (size_t)r * 128
                + (size_t)((kbl ^ (r & 7)) << 4);
    *reinterpret_cast<bf16x8*>(et_hi + byte) = h.v;
    *reinterpret_cast<bf16x8*>(et_lo + byte) = lo.v;
}

// ---------------- P3: z -> zt_hi / zt_lo swizzled tiles (with transpose) ----
__global__ __launch_bounds__(256) void zprep(const float* __restrict__ z,
                                             char* __restrict__ zt_hi,
                                             char* __restrict__ zt_lo) {
    __shared__ float ls[64][65];
    const int bx = blockIdx.x;
    const int mb = bx >> 3, kc = bx & 7;
    const int n0 = mb * 64;
    const int b  = n0 >> 10;
    const int hw0 = n0 & (HW - 1);
    const int t = threadIdx.x;
    const int c4 = t >> 6, lane = t & 63;
    #pragma unroll
    for (int rnd = 0; rnd < 16; ++rnd) {
        int cl = c4 + rnd * 4;
        ls[cl][lane] = z[((size_t)(b * DIM + kc * 64 + cl)) * HW + hw0 + lane];
    }
    __syncthreads();
    size_t tb = ((size_t)mb * 8 + kc) * 8192;
    for (int g = t; g < 512; g += 256) {
        int r = g >> 3, kbl = g & 7;
        PK8 h, lo;
        #pragma unroll
        for (int j = 0; j < 8; ++j) {
            float v = ls[kbl * 8 + j][r];
            ushort hh = bf16_rne(v);
            h.u[j]  = hh;
            lo.u[j] = bf16_rne(v - bf16_to_f(hh));
        }
        size_t byte = tb + (size_t)r * 128 + (size_t)((kbl ^ (r & 7)) << 4);
        *reinterpret_cast<bf16x8*>(zt_hi + byte) = h.v;
        *reinterpret_cast<bf16x8*>(zt_lo + byte) = lo.v;
    }
}

// ---------------- Main: bf16-split MFMA distance + argmin + gather ----------
__global__ __launch_bounds__(256, 2) void vq_mfma(const char* __restrict__ zt_hi,
                                                  const char* __restrict__ zt_lo,
                                                  const char* __restrict__ et_hi,
                                                  const char* __restrict__ et_lo,
                                                  const float* __restrict__ enorm,
                                                  const float* __restrict__ e,
                                                  float* __restrict__ out,
                                                  int* __restrict__ cnt,
                                                  int* __restrict__ list) {
    __shared__ __align__(16) char sAh[8192];
    __shared__ __align__(16) char sAl[8192];
    __shared__ __align__(16) char sBh[16384];
    __shared__ __align__(16) char sBl[16384];
    __shared__ float red_b1[64][2];
    __shared__ float red_b2[64][2];
    __shared__ int   red_i1[64][2];
    __shared__ int   idx_f[64];

    const int t = threadIdx.x;
    const int w = t >> 6, l = t & 63;
    const int lr = l & 15, hg = l >> 4;
    const int wr = (w >> 1) * 32;   // wave row offset (0 or 32)
    const int wc = (w & 1) * 64;    // wave col offset (0 or 64)
    const int mb = blockIdx.x;
    const int n0 = mb * 64;

    float b1[8], b2[8]; int i1[8];
    #pragma unroll
    for (int s = 0; s < 8; ++s) { b1[s] = FLT_MAX; b2[s] = FLT_MAX; i1[s] = 0; }

    const size_t tAbase = (size_t)mb * 8 * 8192;

    for (int nc = 0; nc < 8; ++nc) {
        f32x4 acc[2][4];
        #pragma unroll
        for (int m = 0; m < 2; ++m)
            #pragma unroll
            for (int n = 0; n < 4; ++n) acc[m][n] = (f32x4)(0.f);

        for (int kc = 0; kc < 8; ++kc) {
            __syncthreads();
            {   // stage A (hi+lo: 2x8KB) and B (hi+lo: 2x16KB) linearly
                const char* srcAh = zt_hi + tAbase + (size_t)kc * 8192;
                const char* srcAl = zt_lo + tAbase + (size_t)kc * 8192;
                size_t tB = ((size_t)(nc * 8 + kc)) * 16384;
                const char* srcBh = et_hi + tB;
                const char* srcBl = et_lo + tB;
                #pragma unroll
                for (int p = 0; p < 2; ++p) {
                    int off = (p * 256 + t) * 16;
                    gld16(srcAh + off, sAh + off);
                    gld16(srcAl + off, sAl + off);
                }
                #pragma unroll
                for (int p = 0; p < 4; ++p) {
                    int off = (p * 256 + t) * 16;
                    gld16(srcBh + off, sBh + off);
                    gld16(srcBl + off, sBl + off);
                }
            }
            __syncthreads();
            #pragma unroll
            for (int ks = 0; ks < 2; ++ks) {
                const int kb = ks * 4 + hg;
                bf16x8 ah[2], al[2], bh[4], bl[4];
                #pragma unroll
                for (int m = 0; m < 2; ++m) {
                    int r = wr + m * 16 + lr;
                    int off = r * 128 + ((kb ^ (r & 7)) << 4);
                    ah[m] = *reinterpret_cast<const bf16x8*>(sAh + off);
                    al[m] = *reinterpret_cast<const bf16x8*>(sAl + off);
                }
                #pragma unroll
                for (int n = 0; n < 4; ++n) {
                    int r = wc + n * 16 + lr;
                    int off = r * 128 + ((kb ^ (r & 7)) << 4);
                    bh[n] = *reinterpret_cast<const bf16x8*>(sBh + off);
                    bl[n] = *reinterpret_cast<const bf16x8*>(sBl + off);
                }
                #pragma unroll
                for (int m = 0; m < 2; ++m)
                    #pragma unroll
                    for (int n = 0; n < 4; ++n)
                        acc[m][n] = __builtin_amdgcn_mfma_f32_16x16x32_bf16(ah[m], bh[n], acc[m][n], 0, 0, 0);
                #pragma unroll
                for (int m = 0; m < 2; ++m)
                    #pragma unroll
                    for (int n = 0; n < 4; ++n)
                        acc[m][n] = __builtin_amdgcn_mfma_f32_16x16x32_bf16(ah[m], bl[n], acc[m][n], 0, 0, 0);
                #pragma unroll
                for (int m = 0; m < 2; ++m)
                    #pragma unroll
                    for (int n = 0; n < 4; ++n)
                        acc[m][n] = __builtin_amdgcn_mfma_f32_16x16x32_bf16(al[m], bh[n], acc[m][n], 0, 0, 0);
            }
        }
        // per-nc epilogue: distances + running best-2 argmin
        #pragma unroll
        for (int n = 0; n < 4; ++n) {
            int col = nc * 128 + wc + n * 16 + lr;
            float en = enorm[col];
            #pragma unroll
            for (int m = 0; m < 2; ++m) {
                #pragma unroll
                for (int q = 0; q < 4; ++q) {
                    float dv = en - 2.0f * acc[m][n][q];
                    int s = m * 4 + q;
                    if (dv < b1[s]) { b2[s] = b1[s]; b1[s] = dv; i1[s] = col; }
                    else if (dv < b2[s]) b2[s] = dv;
                }
            }
        }
    }

    // cross-lane butterfly over the 16 column-lanes that share each row
    #pragma unroll
    for (int s = 0; s < 8; ++s) {
        #pragma unroll
        for (int off = 1; off <= 8; off <<= 1) {
            float ob1 = __shfl_xor(b1[s], off, 64);
            int   oi1 = __shfl_xor(i1[s], off, 64);
            float ob2 = __shfl_xor(b2[s], off, 64);
            if (ob1 < b1[s] || (ob1 == b1[s] && oi1 < i1[s])) {
                b2[s] = fminf(b1[s], ob2);
                b1[s] = ob1; i1[s] = oi1;
            } else {
                b2[s] = fminf(b2[s], ob1);
            }
        }
    }
    if (lr == 0) {
        #pragma unroll
        for (int s = 0; s < 8; ++s) {
            int row = wr + (s >> 2) * 16 + hg * 4 + (s & 3);
            red_b1[row][w & 1] = b1[s];
            red_b2[row][w & 1] = b2[s];
            red_i1[row][w & 1] = i1[s];
        }
    }
    __syncthreads();
    if (t < 64) {
        float a1 = red_b1[t][0], a2 = red_b2[t][0]; int ai = red_i1[t][0];
        float c1 = red_b1[t][1], c2 = red_b2[t][1]; int ci = red_i1[t][1];
        float B1, B2; int I1;
        if (c1 < a1 || (c1 == a1 && ci < ai)) { B1 = c1; I1 = ci; B2 = fminf(a1, c2); }
        else                                   { B1 = a1; I1 = ai; B2 = fminf(a2, c1); }
        idx_f[t] = I1;
        out[IOFF + n0 + t] = (float)I1;
        if (B2 - B1 < DELTA) {
            int pos = atomicAdd(cnt, 1);
            list[pos] = n0 + t;
        }
    }
    if (mb == 0 && t == 0) out[SOFF] = 0.0f;
    __syncthreads();

    // gather epilogue: out[b][c][hw0+row] = e[idx[row]][c]
    const int b   = n0 >> 10;
    const int hw0 = n0 & (HW - 1);
    const int row4 = (t & 15) * 4;
    const int i0 = idx_f[row4 + 0];
    const int i1g = idx_f[row4 + 1];
    const int i2 = idx_f[row4 + 2];
    const int i3 = idx_f[row4 + 3];
    #pragma unroll 4
    for (int p = 0; p < 32; ++p) {
        int c = (t >> 4) + (p << 4);
        float4 v;
        v.x = e[(size_t)i0  * DIM + c];
        v.y = e[(size_t)i1g * DIM + c];
        v.z = e[(size_t)i2  * DIM + c];
        v.w = e[(size_t)i3  * DIM + c];
        *reinterpret_cast<float4*>(&out[((size_t)(b * DIM + c)) * HW + hw0 + row4]) = v;
    }
}

// ---------------- Recheck v2: lane-parallel exact fp32 re-scan ----------------
// One block per flagged row (grid-stride). Thread t owns embeddings
// t, t+256, t+512, t+768; each dot = 128 float4 FMAs vs LDS-broadcast zrow.
// No shuffles; one LDS tree-reduction with lowest-index tie-break.
__global__ __launch_bounds__(256) void recheck(const float* __restrict__ z,
                                               const float* __restrict__ e,
                                               const float* __restrict__ enorm,
                                               const int* __restrict__ cnt,
                                               const int* __restrict__ list,
                                               float* __restrict__ out) {
    __shared__ float zrow[512];
    __shared__ float rbest[256];
    __shared__ int   ribi[256];
    __shared__ int   s_fbi;
    const int t = threadIdx.x;
    const int count = *cnt;
    for (int i = blockIdx.x; i < count; i += gridDim.x) {
        const int row = list[i];
        const int b  = row >> 10;
        const int hw = row & (HW - 1);
        __syncthreads();   // guard zrow/rbest reuse across row iterations
        zrow[t]       = z[((size_t)(b * DIM + t))       * HW + hw];
        zrow[t + 256] = z[((size_t)(b * DIM + t + 256)) * HW + hw];
        __syncthreads();
        const float4* zr = reinterpret_cast<const float4*>(zrow);
        float best = FLT_MAX; int bi = 0;
        #pragma unroll
        for (int p = 0; p < 4; ++p) {     // ascending ke => strict < keeps lowest index
            const int ke = t + p * 256;
            const float4* ep = reinterpret_cast<const float4*>(e + (size_t)ke * DIM);
            float s0 = 0.f, s1 = 0.f, s2 = 0.f, s3 = 0.f;
            for (int c = 0; c < 128; c += 4) {
                float4 e0 = ep[c],     z0 = zr[c];
                float4 e1 = ep[c + 1], z1 = zr[c + 1];
                float4 e2 = ep[c + 2], z2 = zr[c + 2];
                float4 e3 = ep[c + 3], z3 = zr[c + 3];
                s0 += e0.x*z0.x + e0.y*z0.y + e0.z*z0.z + e0.w*z0.w;
                s1 += e1.x*z1.x + e1.y*z1.y + e1.z*z1.z + e1.w*z1.w;
                s2 += e2.x*z2.x + e2.y*z2.y + e2.z*z2.z + e2.w*z2.w;
                s3 += e3.x*z3.x + e3.y*z3.y + e3.z*z3.z + e3.w*z3.w;
            }
            float dist = enorm[ke] - 2.0f * (((s0 + s1) + (s2 + s3)));
            if (dist < best) { best = dist; bi = ke; }
        }
        rbest[t] = best; ribi[t] = bi;
        __syncthreads();
        #pragma unroll
        for (int s = 128; s > 0; s >>= 1) {
            if (t < s) {
                float ov = rbest[t + s]; int oi = ribi[t + s];
                if (ov < rbest[t] || (ov == rbest[t] && oi < ribi[t])) {
                    rbest[t] = ov; ribi[t] = oi;
                }
            }
            __syncthreads();
        }
        if (t == 0) {
            s_fbi = ribi[0];
            out[IOFF + row] = (float)ribi[0];
        }
        __syncthreads();
        const int fbi = s_fbi;
        out[((size_t)(b * DIM + t))       * HW + hw] = e[(size_t)fbi * DIM + t];
        out[((size_t)(b * DIM + t + 256)) * HW + hw] = e[(size_t)fbi * DIM + t + 256];
    }
}

// ======================= fp32 fallback path (round-2, proven) ================
constexpr int TM = 64;
constexpr int TN = 256;
constexpr int KC = 32;
constexpr int ZST = 68;
constexpr int EST = 260;

union F4 { float4 v; float f[4]; };

__global__ __launch_bounds__(256) void enorm_kernel(const float* __restrict__ e,
                                                    float* __restrict__ enorm) {
    int gid  = blockIdx.x * 256 + threadIdx.x;
    int wave = gid >> 6;
    int lane = gid & 63;
    if (wave >= NEMB) return;
    const float* row = e + (size_t)wave * DIM;
    float4 a = *reinterpret_cast<const float4*>(row + lane * 8);
    float4 b = *reinterpret_cast<const float4*>(row + lane * 8 + 4);
    float s = a.x*a.x + a.y*a.y + a.z*a.z + a.w*a.w
            + b.x*b.x + b.y*b.y + b.z*b.z + b.w*b.w;
    #pragma unroll
    for (int off = 32; off > 0; off >>= 1) s += __shfl_down(s, off, 64);
    if (lane == 0) enorm[wave] = s;
}

__global__ __launch_bounds__(256) void vq_main_kernel(const float* __restrict__ z,
                                                      const float* __restrict__ e,
                                                      const float* __restrict__ enorm,
                                                      float* __restrict__ out) {
    __shared__ float zs[KC][ZST];
    __shared__ float es[KC][EST];
    __shared__ float enorm_l[NEMB];
    __shared__ int   idx_f[TM];

    const int t   = threadIdx.x;
    const int n0  = blockIdx.x * TM;
    const int b   = n0 >> 10;
    const int hw0 = n0 & (HW - 1);
    const float* zb = z + ((size_t)b * DIM) * HW + hw0;

    #pragma unroll
    for (int i = 0; i < 4; ++i) enorm_l[t + i * 256] = enorm[t + i * 256];

    const int rg = t >> 5;
    const int cg = t & 31;

    float best[8];
    int   bidx[8];
    #pragma unroll
    for (int i = 0; i < 8; ++i) { best[i] = FLT_MAX; bidx[i] = 0; }

    const int z_r4 = (t & 15) * 4;
    const int z_c  = t >> 4;
    const int e_ke = t >> 3;
    const int e_c4 = t & 7;

    for (int nc = 0; nc < NEMB / TN; ++nc) {
        const int k0 = nc * TN;
        float acc[8][8];
        #pragma unroll
        for (int mi = 0; mi < 8; ++mi)
            #pragma unroll
            for (int nj = 0; nj < 8; ++nj) acc[mi][nj] = 0.f;

        for (int kc = 0; kc < DIM / KC; ++kc) {
            const int c0 = kc * KC;
            __syncthreads();
            #pragma unroll
            for (int p = 0; p < 2; ++p) {
                int c = z_c + p * 16;
                float4 v = *reinterpret_cast<const float4*>(zb + (size_t)(c0 + c) * HW + z_r4);
                *reinterpret_cast<float4*>(&zs[c][z_r4]) = v;
            }
            #pragma unroll
            for (int p = 0; p < 8; ++p) {
                int ke = e_ke + p * 32;
                float4 v = *reinterpret_cast<const float4*>(e + (size_t)(k0 + ke) * DIM + c0 + e_c4 * 4);
                es[e_c4 * 4 + 0][ke] = v.x;
                es[e_c4 * 4 + 1][ke] = v.y;
                es[e_c4 * 4 + 2][ke] = v.z;
                es[e_c4 * 4 + 3][ke] = v.w;
            }
            __syncthreads();
            #pragma unroll
            for (int kk = 0; kk < KC; ++kk) {
                F4 zf0, zf1, ef0, ef1;
                zf0.v = *reinterpret_cast<const float4*>(&zs[kk][rg * 8]);
                zf1.v = *reinterpret_cast<const float4*>(&zs[kk][rg * 8 + 4]);
                ef0.v = *reinterpret_cast<const float4*>(&es[kk][cg * 4]);
                ef1.v = *reinterpret_cast<const float4*>(&es[kk][128 + cg * 4]);
                #pragma unroll
                for (int mi = 0; mi < 4; ++mi) {
                    #pragma unroll
                    for (int nj = 0; nj < 4; ++nj) {
                        acc[mi][nj]         += zf0.f[mi] * ef0.f[nj];
                        acc[mi][nj + 4]     += zf0.f[mi] * ef1.f[nj];
                        acc[mi + 4][nj]     += zf1.f[mi] * ef0.f[nj];
                        acc[mi + 4][nj + 4] += zf1.f[mi] * ef1.f[nj];
                    }
                }
            }
        }
        #pragma unroll
        for (int mi = 0; mi < 8; ++mi) {
            #pragma unroll
            for (int nj = 0; nj < 8; ++nj) {
                int col = k0 + (nj < 4 ? cg * 4 + nj : 128 + cg * 4 + (nj - 4));
                float dv = enorm_l[col] - 2.0f * acc[mi][nj];
                if (dv < best[mi]) { best[mi] = dv; bidx[mi] = col; }
            }
        }
    }

    __syncthreads();
    float* best_l = reinterpret_cast<float*>(es);
    int*   idx_l  = reinterpret_cast<int*>(reinterpret_cast<char*>(es) + (size_t)TM * 33 * 4);
    #pragma unroll
    for (int mi = 0; mi < 8; ++mi) {
        int row = rg * 8 + mi;
        best_l[row * 33 + cg] = best[mi];
        idx_l[row * 33 + cg]  = bidx[mi];
    }
    __syncthreads();
    if (t < TM) {
        float bv = best_l[t * 33];
        int   bi = idx_l[t * 33];
        #pragma unroll
        for (int c = 1; c < 32; ++c) {
            float v  = best_l[t * 33 + c];
            int   ix = idx_l[t * 33 + c];
            if (v < bv || (v == bv && ix < bi)) { bv = v; bi = ix; }
        }
        idx_f[t] = bi;
        out[IOFF + n0 + t] = (float)bi;
    }
    if (blockIdx.x == 0 && t == 0) out[SOFF] = 0.0f;
    __syncthreads();

    const int row4 = (t & 15) * 4;
    const int i0 = idx_f[row4 + 0];
    const int i1 = idx_f[row4 + 1];
    const int i2 = idx_f[row4 + 2];
    const int i3 = idx_f[row4 + 3];
    #pragma unroll 4
    for (int p = 0; p < 32; ++p) {
        int c = (t >> 4) + (p << 4);
        float4 v;
        v.x = e[(size_t)i0 * DIM + c];
        v.y = e[(size_t)i1 * DIM + c];
        v.z = e[(size_t)i2 * DIM + c];
        v.w = e[(size_t)i3 * DIM + c];
        *reinterpret_cast<float4*>(&out[((size_t)(b * DIM + c)) * HW + hw0 + row4]) = v;
    }
}

// ---------------- host launcher ----------------
extern "C" void kernel_launch(void* const* d_in, const int* in_sizes, int n_in,
                              void* d_out, int out_size, void* d_ws, size_t ws_size,
                              hipStream_t stream) {
    const float* z = (const float*)d_in[0];
    const float* e = (const float*)d_in[1];
    float* out = (float*)d_out;
    char*  ws  = (char*)d_ws;

    if (ws_size >= WS_NEED) {
        char*  zt_hi = ws + WS_ZHI;
        char*  zt_lo = ws + WS_ZLO;
        char*  et_hi = ws + WS_EHI;
        char*  et_lo = ws + WS_ELO;
        float* enorm = (float*)(ws + WS_ENORM);
        int*   cnt   = (int*)(ws + WS_CNT);
        int*   list  = (int*)(ws + WS_LIST);

        hipLaunchKernelGGL(enorm_prep, dim3(NEMB / 4), dim3(256), 0, stream, e, enorm, cnt);
        hipLaunchKernelGGL(eprep,      dim3(256),      dim3(256), 0, stream, e, et_hi, et_lo);
        hipLaunchKernelGGL(zprep,      dim3(4096),     dim3(256), 0, stream, z, zt_hi, zt_lo);
        hipLaunchKernelGGL(vq_mfma,    dim3(NROW / 64), dim3(256), 0, stream,
                           zt_hi, zt_lo, et_hi, et_lo, enorm, e, out, cnt, list);
        hipLaunchKernelGGL(recheck,    dim3(256),      dim3(256), 0, stream,
                           z, e, enorm, cnt, list, out);
    } else {
        float* enorm = (float*)ws;
        hipLaunchKernelGGL(enorm_kernel,   dim3(NEMB / 4), dim3(256), 0, stream, e, enorm);
        hipLaunchKernelGGL(vq_main_kernel, dim3(NROW / TM), dim3(256), 0, stream,
                           z, e, enorm, out);
    }
}